// Round 11
// baseline (213.623 us; speedup 1.0000x reference)
//
#include <hip/hip_runtime.h>
#include <cmath>

// GCN 2-layer: N=100k, E=3.2M, 5 -> 16 (relu) -> 3.
// R11: bscatter's 65us was its LDS rank-atomic pass starved at 196 blocks
// (0.77/CU, occupancy 7%): LDS-atomic rate scales with resident waves.
// VPT 64->16 -> 782 blocks (3/CU). Claims rise 77K->306K on padded lines
// (~+4us) - fine trade. sortdeg/agg unchanged (want clean dispatch numbers).
// Pipeline: bucket edges by dst>>8 -> per-bucket counting sort by node ->
// register-accumulated gather aggregation (zero LDS atomics in agg).
// Factorization: agg[d] = dinv[d]*(xd[d] + sum_e xd[src_e]) @ W1, xd=x*dinv.

constexpr int BLK   = 256;
constexpr int VPT   = 16;    // edges/thread in bscatter (4096/block, 782 blocks)
constexpr int GPAD  = 16;    // gcurs: one counter per 64B line
constexpr int MAXIT = 9;     // sortdeg edges/thread ceiling (stride <= 9216)

__global__ void k_init(int* __restrict__ gcurs, int NB, int stride) {
    int i = blockIdx.x * BLK + threadIdx.x;
    if (i < NB) gcurs[i * GPAD] = i * stride;
}

// Partition edges into dst>>8 buckets (order within bucket arbitrary).
__global__ __launch_bounds__(BLK) void k_bscatter(
        const int* __restrict__ src, const int* __restrict__ dst,
        int* __restrict__ gcurs, int* __restrict__ bpack,
        int E, int NB, int stride) {
    __shared__ int lcnt[512];
    __shared__ int lbase[512];
    int tid = threadIdx.x;
    for (int i = tid; i < 512; i += BLK) lcnt[i] = 0;
    __syncthreads();
    int e0 = blockIdx.x * (BLK * VPT);
    int pk[VPT];                     // (rank<<9)|bucket ; rank < 4096
#pragma unroll
    for (int j = 0; j < VPT; ++j) {
        int e = e0 + j * BLK + tid;
        if (e < E) {
            int b = dst[e] >> 8;
            int r = atomicAdd(&lcnt[b], 1);
            pk[j] = (r << 9) | b;
        } else pk[j] = -1;
    }
    __syncthreads();
    for (int i = tid; i < NB; i += BLK) {
        int c = lcnt[i];
        lbase[i] = c ? atomicAdd(&gcurs[i * GPAD], c) : 0;
    }
    __syncthreads();
#pragma unroll
    for (int j = 0; j < VPT; ++j) {
        if (pk[j] >= 0) {
            int e = e0 + j * BLK + tid;          // reload src/dst (L2-hot)
            int b = pk[j] & 511, r = pk[j] >> 9;
            int p = lbase[b] + r;
            if (p < (b + 1) * stride)            // 8+ sigma overflow guard
                bpack[p] = (src[e] << 8) | (dst[e] & 255);
        }
    }
}

// Per bucket: count degrees (atomicAdd returns within-node rank), block scan
// -> counting sort of srcs into per-node CSR runs (ssrc + nstart). Also
// writes dinv and xd8 = {x*dinv, pad to 32B}. One int LDS atomic per edge.
__global__ __launch_bounds__(1024) void k_sortdeg(
        const int* __restrict__ gcurs, const int* __restrict__ bpack,
        const float* __restrict__ x, float* __restrict__ dinv,
        float* __restrict__ xd8, int* __restrict__ ssrc,
        int* __restrict__ nstart, int N, int stride) {
    __shared__ int cnt[256];
    __shared__ int scan[256];
    int tid = threadIdx.x, b = blockIdx.x;
    if (tid < 256) cnt[tid] = 0;
    __syncthreads();
    int beg = b * stride;
    int end = min(gcurs[b * GPAD], beg + stride);
    int rk[MAXIT], pkv[MAXIT];
#pragma unroll
    for (int j = 0; j < MAXIT; ++j) {
        int e = beg + j * 1024 + tid;
        bool v = e < end;
        int pk = v ? bpack[e] : 0;
        pkv[j] = pk;
        rk[j] = v ? atomicAdd(&cnt[pk & 255], 1) : 0;
    }
    __syncthreads();
    if (tid < 256) scan[tid] = cnt[tid];
    __syncthreads();
    for (int off = 1; off < 256; off <<= 1) {    // inclusive Hillis-Steele
        int v = 0;
        if (tid < 256 && tid >= off) v = scan[tid - off];
        __syncthreads();
        if (tid < 256) scan[tid] += v;
        __syncthreads();
    }
    // excl[d] = scan[d] - cnt[d]
#pragma unroll
    for (int j = 0; j < MAXIT; ++j) {
        int e = beg + j * 1024 + tid;
        if (e < end) {
            int d = pkv[j] & 255;
            int p = beg + scan[d] - cnt[d] + rk[j];
            ssrc[p] = pkv[j] >> 8;
        }
    }
    if (tid >= 256) return;
    nstart[b * 256 + tid] = beg + scan[tid] - cnt[tid];
    int node = b * 256 + tid;
    if (node >= N) return;
    float di = rsqrtf((float)(cnt[tid] + 1));    // +1 self-loop
    dinv[node] = di;
    float4 lo, hi;
    lo.x = x[(size_t)node * 5 + 0] * di;
    lo.y = x[(size_t)node * 5 + 1] * di;
    lo.z = x[(size_t)node * 5 + 2] * di;
    lo.w = x[(size_t)node * 5 + 3] * di;
    hi.x = x[(size_t)node * 5 + 4] * di;
    hi.y = 0.f; hi.z = 0.f; hi.w = 0.f;
    float4* o = reinterpret_cast<float4*>(xd8) + (size_t)node * 2;
    o[0] = lo; o[1] = hi;
}

// Layer-1 aggregate: 4 lanes per node walk its CSR run, register-accumulate
// 5 floats, shfl quad-reduce. Epilogue: +self, *dinv, @W1+b1, relu, @W2,
// *dinv -> hs2. No LDS atomics.
__global__ __launch_bounds__(1024) void k_agg1(
        const float* __restrict__ xd8, const int* __restrict__ gcurs,
        const int* __restrict__ ssrc, const int* __restrict__ nstart,
        const float* __restrict__ dinv, const float* __restrict__ W1,
        const float* __restrict__ b1, const float* __restrict__ W2,
        float* __restrict__ hs2, int N, int stride) {
    __shared__ float w1[80];
    __shared__ float w2[48];
    int tid = threadIdx.x, b = blockIdx.x;
    if (tid < 80) w1[tid] = W1[tid];
    else if (tid >= 128 && tid < 176) w2[tid - 128] = W2[tid - 128];
    __syncthreads();
    int n = tid >> 2, q = tid & 3;
    int node = b * 256 + n;
    int beg = b * stride;
    int bend = min(gcurs[b * GPAD], beg + stride);
    int s0 = nstart[b * 256 + n];
    int s1 = (n < 255) ? nstart[b * 256 + n + 1] : bend;
    const float4* h4 = reinterpret_cast<const float4*>(xd8);
    float g0 = 0.f, g1 = 0.f, g2 = 0.f, g3 = 0.f, g4 = 0.f;
    int e = s0 + q;
    int sN = (e < s1) ? ssrc[e] : 0;             // 1-deep index prefetch
    while (e < s1) {
        int s = sN;
        int e2 = e + 4;
        sN = (e2 < s1) ? ssrc[e2] : 0;
        float4 lo = h4[(size_t)s * 2];
        float v4 = xd8[(size_t)s * 8 + 4];
        g0 += lo.x; g1 += lo.y; g2 += lo.z; g3 += lo.w; g4 += v4;
        e = e2;
    }
    g0 += __shfl_xor(g0, 1); g0 += __shfl_xor(g0, 2);
    g1 += __shfl_xor(g1, 1); g1 += __shfl_xor(g1, 2);
    g2 += __shfl_xor(g2, 1); g2 += __shfl_xor(g2, 2);
    g3 += __shfl_xor(g3, 1); g3 += __shfl_xor(g3, 2);
    g4 += __shfl_xor(g4, 1); g4 += __shfl_xor(g4, 2);
    if (q != 0 || node >= N) return;
    float di = dinv[node];
    const float* xs = &xd8[(size_t)node * 8];
    g0 += xs[0]; g1 += xs[1]; g2 += xs[2]; g3 += xs[3]; g4 += xs[4];
    float p0 = 0.f, p1 = 0.f, p2 = 0.f;
#pragma unroll
    for (int f = 0; f < 16; ++f) {
        float s = g0 * w1[f] + g1 * w1[16 + f] + g2 * w1[32 + f]
                + g3 * w1[48 + f] + g4 * w1[64 + f];
        float t = fmaxf(fmaf(di, s, b1[f]), 0.f);
        p0 = fmaf(t, w2[f * 3 + 0], p0);
        p1 = fmaf(t, w2[f * 3 + 1], p1);
        p2 = fmaf(t, w2[f * 3 + 2], p2);
    }
    float4 o = {p0 * di, p1 * di, p2 * di, 0.f};
    *reinterpret_cast<float4*>(&hs2[(size_t)node * 4]) = o;
}

// Layer-2 aggregate: same structure over hs2 (16B rows). No LDS atomics.
__global__ __launch_bounds__(1024) void k_agg2(
        const float* __restrict__ hs2, const int* __restrict__ gcurs,
        const int* __restrict__ ssrc, const int* __restrict__ nstart,
        const float* __restrict__ dinv, const float* __restrict__ b2,
        float* __restrict__ out, int N, int stride) {
    int tid = threadIdx.x, b = blockIdx.x;
    int n = tid >> 2, q = tid & 3;
    int node = b * 256 + n;
    int beg = b * stride;
    int bend = min(gcurs[b * GPAD], beg + stride);
    int s0 = nstart[b * 256 + n];
    int s1 = (n < 255) ? nstart[b * 256 + n + 1] : bend;
    const float4* h4 = reinterpret_cast<const float4*>(hs2);
    float a0 = 0.f, a1 = 0.f, a2 = 0.f;
    int e = s0 + q;
    int sN = (e < s1) ? ssrc[e] : 0;
    while (e < s1) {
        int s = sN;
        int e2 = e + 4;
        sN = (e2 < s1) ? ssrc[e2] : 0;
        float4 v = h4[s];
        a0 += v.x; a1 += v.y; a2 += v.z;
        e = e2;
    }
    a0 += __shfl_xor(a0, 1); a0 += __shfl_xor(a0, 2);
    a1 += __shfl_xor(a1, 1); a1 += __shfl_xor(a1, 2);
    a2 += __shfl_xor(a2, 1); a2 += __shfl_xor(a2, 2);
    if (q != 0 || node >= N) return;
    float di = dinv[node];
    const float* hself = &hs2[(size_t)node * 4];
    out[(size_t)node * 3 + 0] = fmaf(di, a0 + hself[0], b2[0]);
    out[(size_t)node * 3 + 1] = fmaf(di, a1 + hself[1], b2[1]);
    out[(size_t)node * 3 + 2] = fmaf(di, a2 + hself[2], b2[2]);
}

// ---- launch ----------------------------------------------------------------

extern "C" void kernel_launch(void* const* d_in, const int* in_sizes, int n_in,
                              void* d_out, int out_size, void* d_ws, size_t ws_size,
                              hipStream_t stream) {
    const float* x  = (const float*)d_in[0];
    const int*   ei = (const int*)  d_in[1];
    const float* W1 = (const float*)d_in[2];
    const float* b1 = (const float*)d_in[3];
    const float* W2 = (const float*)d_in[4];
    const float* b2 = (const float*)d_in[5];
    float* out = (float*)d_out;

    const int N = in_sizes[0] / 5;
    const int E = in_sizes[1] / 2;
    const int* src = ei;
    const int* dst = ei + E;

    const int NB = (N + 255) >> 8;                       // 391 buckets
    int mean = (E + NB - 1) / NB;                        // ~8185
    int stride = mean + (int)(8.0 * sqrt((double)mean)) + 64;
    stride = (stride + 63) & ~63;                        // ~9024
    if (stride > 1024 * MAXIT) stride = 1024 * MAXIT;    // sortdeg reg ceiling

    // Workspace (16B aligned), ~34MB total.
    char* ws = (char*)d_ws;
    size_t off = 0;
    auto alloc = [&](size_t bytes) -> void* {
        void* p = ws + off;
        off += (bytes + 15) & ~size_t(15);
        return p;
    };
    int*   gcurs  = (int*)  alloc((size_t)NB * GPAD * 4);
    int*   bpack  = (int*)  alloc((size_t)NB * stride * 4);
    int*   ssrc   = (int*)  alloc((size_t)NB * stride * 4);
    int*   nstart = (int*)  alloc((size_t)NB * 256 * 4);
    float* dinv   = (float*)alloc((size_t)N * 4);
    float* xd8    = (float*)alloc((size_t)N * 8 * 4);
    float* hs2    = (float*)alloc((size_t)N * 4 * 4);
    (void)ws_size; (void)n_in; (void)out_size;

    const int gInit = (NB + BLK - 1) / BLK;
    const int gScat = (E + BLK * VPT - 1) / (BLK * VPT); // 782

    k_init    <<<gInit, BLK,  0, stream>>>(gcurs, NB, stride);
    k_bscatter<<<gScat, BLK,  0, stream>>>(src, dst, gcurs, bpack, E, NB, stride);
    k_sortdeg <<<NB,    1024, 0, stream>>>(gcurs, bpack, x, dinv, xd8, ssrc, nstart, N, stride);
    k_agg1    <<<NB,    1024, 0, stream>>>(xd8, gcurs, ssrc, nstart, dinv, W1, b1, W2, hs2, N, stride);
    k_agg2    <<<NB,    1024, 0, stream>>>(hs2, gcurs, ssrc, nstart, dinv, b2, out, N, stride);
}

// Round 12
// 195.211 us; speedup vs baseline: 1.0943x; 1.0943x over previous
//
#include <hip/hip_runtime.h>
#include <cmath>

// GCN 2-layer: N=100k, E=3.2M, 5 -> 16 (relu) -> 3.
// R12: bscatter's R11 regression was cross-XCD write amplification (73-86MB
// for a 12.8MB payload): 782 claimers sharing frontier lines across 8
// non-coherent L2s. Fix: 8 per-XCD sub-frontiers per bucket (sub=blockIdx&7
// tracks round-robin XCD assignment) -> claims+writes stay XCD-local, while
// keeping VPT=16's 782-block parallelism for the LDS rank pass.
// Pipeline: bucket edges by dst>>8 -> per-bucket counting sort by node ->
// register-accumulated gather aggregation (zero LDS atomics in agg).
// Factorization: agg[d] = dinv[d]*(xd[d] + sum_e xd[src_e]) @ W1, xd=x*dinv.

constexpr int BLK   = 256;
constexpr int VPT   = 16;    // edges/thread in bscatter (4096/block, 782 blocks)
constexpr int GPAD  = 16;    // cursors: one per 64B line
constexpr int NSUB  = 8;     // per-XCD sub-frontiers per bucket
constexpr int MAXIT = 10;    // sortdeg: stride <= 10240

// cursors: gcurs[(b*8+r)*GPAD] = b*stride + r*substride
__global__ void k_init(int* __restrict__ gcurs, int NC, int stride, int substride) {
    int i = blockIdx.x * BLK + threadIdx.x;
    if (i < NC) gcurs[i * GPAD] = (i >> 3) * stride + (i & 7) * substride;
}

// Partition edges into dst>>8 buckets; each block writes only its own
// XCD sub-region of every bucket.
__global__ __launch_bounds__(BLK) void k_bscatter(
        const int* __restrict__ src, const int* __restrict__ dst,
        int* __restrict__ gcurs, int* __restrict__ bpack,
        int E, int NB, int stride, int substride) {
    __shared__ int lcnt[512];
    __shared__ int lbase[512];
    int tid = threadIdx.x;
    int sub = blockIdx.x & (NSUB - 1);
    for (int i = tid; i < 512; i += BLK) lcnt[i] = 0;
    __syncthreads();
    int e0 = blockIdx.x * (BLK * VPT);
    int pk[VPT];                     // (rank<<9)|bucket ; rank < 4096
#pragma unroll
    for (int j = 0; j < VPT; ++j) {
        int e = e0 + j * BLK + tid;
        if (e < E) {
            int b = dst[e] >> 8;
            int r = atomicAdd(&lcnt[b], 1);
            pk[j] = (r << 9) | b;
        } else pk[j] = -1;
    }
    __syncthreads();
    for (int i = tid; i < NB; i += BLK) {
        int c = lcnt[i];
        lbase[i] = c ? atomicAdd(&gcurs[(i * NSUB + sub) * GPAD], c) : 0;
    }
    __syncthreads();
#pragma unroll
    for (int j = 0; j < VPT; ++j) {
        if (pk[j] >= 0) {
            int e = e0 + j * BLK + tid;          // reload src/dst (L2-hot)
            int b = pk[j] & 511, r = pk[j] >> 9;
            int p = lbase[b] + r;
            if (p < b * stride + (sub + 1) * substride)  // 8-sigma guard
                bpack[p] = (src[e] << 8) | (dst[e] & 255);
        }
    }
}

// Per bucket: count degrees over the 8 sub-ranges (atomicAdd returns
// within-node rank), block scan -> counting sort into per-node CSR runs
// (ssrc + nstart[257/bucket]). Also writes dinv and xd8 = {x*dinv, pad 32B}.
__global__ __launch_bounds__(1024) void k_sortdeg(
        const int* __restrict__ gcurs, const int* __restrict__ bpack,
        const float* __restrict__ x, float* __restrict__ dinv,
        float* __restrict__ xd8, int* __restrict__ ssrc,
        int* __restrict__ nstart, int N, int stride, int substride, int subrecip) {
    __shared__ int cnt[256];
    __shared__ int scan[256];
    __shared__ int subend[NSUB];
    int tid = threadIdx.x, b = blockIdx.x;
    if (tid < 256) cnt[tid] = 0;
    if (tid >= 256 && tid < 256 + NSUB) {
        int r = tid - 256;
        int sb = b * stride + r * substride;
        subend[r] = min(gcurs[(b * NSUB + r) * GPAD], sb + substride);
    }
    __syncthreads();
    int beg = b * stride;
    int rk[MAXIT], pkv[MAXIT];
    bool va[MAXIT];
#pragma unroll
    for (int j = 0; j < MAXIT; ++j) {
        int off = j * 1024 + tid;                // 0 .. stride-1
        int r = (off * subrecip) >> 24;          // off / substride (magic)
        int e = beg + off;
        bool v = (off < NSUB * substride) && (e < subend[r]);
        va[j] = v;
        int pk = v ? bpack[e] : 0;
        pkv[j] = pk;
        rk[j] = v ? atomicAdd(&cnt[pk & 255], 1) : 0;
    }
    __syncthreads();
    if (tid < 256) scan[tid] = cnt[tid];
    __syncthreads();
    for (int off = 1; off < 256; off <<= 1) {    // inclusive Hillis-Steele
        int v = 0;
        if (tid < 256 && tid >= off) v = scan[tid - off];
        __syncthreads();
        if (tid < 256) scan[tid] += v;
        __syncthreads();
    }
#pragma unroll
    for (int j = 0; j < MAXIT; ++j) {
        if (va[j]) {
            int d = pkv[j] & 255;
            int p = beg + scan[d] - cnt[d] + rk[j];   // excl prefix + rank
            ssrc[p] = pkv[j] >> 8;
        }
    }
    if (tid >= 256) return;
    nstart[b * 257 + tid] = beg + scan[tid] - cnt[tid];
    if (tid == 255) nstart[b * 257 + 256] = beg + scan[255];
    int node = b * 256 + tid;
    if (node >= N) return;
    float di = rsqrtf((float)(cnt[tid] + 1));    // +1 self-loop
    dinv[node] = di;
    float4 lo, hi;
    lo.x = x[(size_t)node * 5 + 0] * di;
    lo.y = x[(size_t)node * 5 + 1] * di;
    lo.z = x[(size_t)node * 5 + 2] * di;
    lo.w = x[(size_t)node * 5 + 3] * di;
    hi.x = x[(size_t)node * 5 + 4] * di;
    hi.y = 0.f; hi.z = 0.f; hi.w = 0.f;
    float4* o = reinterpret_cast<float4*>(xd8) + (size_t)node * 2;
    o[0] = lo; o[1] = hi;
}

// Layer-1 aggregate: 4 lanes per node walk its CSR run, register-accumulate
// 5 floats, shfl quad-reduce. Epilogue: +self, *dinv, @W1+b1, relu, @W2,
// *dinv -> hs2. No LDS atomics.
__global__ __launch_bounds__(1024) void k_agg1(
        const float* __restrict__ xd8, const int* __restrict__ ssrc,
        const int* __restrict__ nstart, const float* __restrict__ dinv,
        const float* __restrict__ W1, const float* __restrict__ b1,
        const float* __restrict__ W2, float* __restrict__ hs2, int N) {
    __shared__ float w1[80];
    __shared__ float w2[48];
    int tid = threadIdx.x, b = blockIdx.x;
    if (tid < 80) w1[tid] = W1[tid];
    else if (tid >= 128 && tid < 176) w2[tid - 128] = W2[tid - 128];
    __syncthreads();
    int n = tid >> 2, q = tid & 3;
    int node = b * 256 + n;
    int s0 = nstart[b * 257 + n];
    int s1 = nstart[b * 257 + n + 1];
    const float4* h4 = reinterpret_cast<const float4*>(xd8);
    float g0 = 0.f, g1 = 0.f, g2 = 0.f, g3 = 0.f, g4 = 0.f;
    int e = s0 + q;
    int sN = (e < s1) ? ssrc[e] : 0;             // 1-deep index prefetch
    while (e < s1) {
        int s = sN;
        int e2 = e + 4;
        sN = (e2 < s1) ? ssrc[e2] : 0;
        float4 lo = h4[(size_t)s * 2];
        float v4 = xd8[(size_t)s * 8 + 4];
        g0 += lo.x; g1 += lo.y; g2 += lo.z; g3 += lo.w; g4 += v4;
        e = e2;
    }
    g0 += __shfl_xor(g0, 1); g0 += __shfl_xor(g0, 2);
    g1 += __shfl_xor(g1, 1); g1 += __shfl_xor(g1, 2);
    g2 += __shfl_xor(g2, 1); g2 += __shfl_xor(g2, 2);
    g3 += __shfl_xor(g3, 1); g3 += __shfl_xor(g3, 2);
    g4 += __shfl_xor(g4, 1); g4 += __shfl_xor(g4, 2);
    if (q != 0 || node >= N) return;
    float di = dinv[node];
    const float* xs = &xd8[(size_t)node * 8];
    g0 += xs[0]; g1 += xs[1]; g2 += xs[2]; g3 += xs[3]; g4 += xs[4];
    float p0 = 0.f, p1 = 0.f, p2 = 0.f;
#pragma unroll
    for (int f = 0; f < 16; ++f) {
        float s = g0 * w1[f] + g1 * w1[16 + f] + g2 * w1[32 + f]
                + g3 * w1[48 + f] + g4 * w1[64 + f];
        float t = fmaxf(fmaf(di, s, b1[f]), 0.f);
        p0 = fmaf(t, w2[f * 3 + 0], p0);
        p1 = fmaf(t, w2[f * 3 + 1], p1);
        p2 = fmaf(t, w2[f * 3 + 2], p2);
    }
    float4 o = {p0 * di, p1 * di, p2 * di, 0.f};
    *reinterpret_cast<float4*>(&hs2[(size_t)node * 4]) = o;
}

// Layer-2 aggregate: same structure over hs2 (16B rows). No LDS atomics.
__global__ __launch_bounds__(1024) void k_agg2(
        const float* __restrict__ hs2, const int* __restrict__ ssrc,
        const int* __restrict__ nstart, const float* __restrict__ dinv,
        const float* __restrict__ b2, float* __restrict__ out, int N) {
    int tid = threadIdx.x, b = blockIdx.x;
    int n = tid >> 2, q = tid & 3;
    int node = b * 256 + n;
    int s0 = nstart[b * 257 + n];
    int s1 = nstart[b * 257 + n + 1];
    const float4* h4 = reinterpret_cast<const float4*>(hs2);
    float a0 = 0.f, a1 = 0.f, a2 = 0.f;
    int e = s0 + q;
    int sN = (e < s1) ? ssrc[e] : 0;
    while (e < s1) {
        int s = sN;
        int e2 = e + 4;
        sN = (e2 < s1) ? ssrc[e2] : 0;
        float4 v = h4[s];
        a0 += v.x; a1 += v.y; a2 += v.z;
        e = e2;
    }
    a0 += __shfl_xor(a0, 1); a0 += __shfl_xor(a0, 2);
    a1 += __shfl_xor(a1, 1); a1 += __shfl_xor(a1, 2);
    a2 += __shfl_xor(a2, 1); a2 += __shfl_xor(a2, 2);
    if (q != 0 || node >= N) return;
    float di = dinv[node];
    const float* hself = &hs2[(size_t)node * 4];
    out[(size_t)node * 3 + 0] = fmaf(di, a0 + hself[0], b2[0]);
    out[(size_t)node * 3 + 1] = fmaf(di, a1 + hself[1], b2[1]);
    out[(size_t)node * 3 + 2] = fmaf(di, a2 + hself[2], b2[2]);
}

// ---- launch ----------------------------------------------------------------

extern "C" void kernel_launch(void* const* d_in, const int* in_sizes, int n_in,
                              void* d_out, int out_size, void* d_ws, size_t ws_size,
                              hipStream_t stream) {
    const float* x  = (const float*)d_in[0];
    const int*   ei = (const int*)  d_in[1];
    const float* W1 = (const float*)d_in[2];
    const float* b1 = (const float*)d_in[3];
    const float* W2 = (const float*)d_in[4];
    const float* b2 = (const float*)d_in[5];
    float* out = (float*)d_out;

    const int N = in_sizes[0] / 5;
    const int E = in_sizes[1] / 2;
    const int* src = ei;
    const int* dst = ei + E;

    const int NB = (N + 255) >> 8;                       // 391 buckets
    int meanSub = (E + NB * NSUB - 1) / (NB * NSUB);     // ~1023 edges/(bkt,xcd)
    int substride = meanSub + (int)(8.0 * sqrt((double)meanSub)) + 1;
    substride = (substride + 63) & ~63;                  // 1280
    if (substride * NSUB > 1024 * MAXIT) substride = (1024 * MAXIT) / NSUB;
    int stride = substride * NSUB;                       // 10240
    int subrecip = ((1 << 24) + substride - 1) / substride;  // magic for /substride

    // Workspace (16B aligned), ~38MB total.
    char* ws = (char*)d_ws;
    size_t off = 0;
    auto alloc = [&](size_t bytes) -> void* {
        void* p = ws + off;
        off += (bytes + 15) & ~size_t(15);
        return p;
    };
    int*   gcurs  = (int*)  alloc((size_t)NB * NSUB * GPAD * 4);
    int*   bpack  = (int*)  alloc((size_t)NB * stride * 4);
    int*   ssrc   = (int*)  alloc((size_t)NB * stride * 4);
    int*   nstart = (int*)  alloc((size_t)NB * 257 * 4);
    float* dinv   = (float*)alloc((size_t)N * 4);
    float* xd8    = (float*)alloc((size_t)N * 8 * 4);
    float* hs2    = (float*)alloc((size_t)N * 4 * 4);
    (void)ws_size; (void)n_in; (void)out_size;

    const int NC    = NB * NSUB;                         // 3128 cursors
    const int gInit = (NC + BLK - 1) / BLK;
    const int gScat = (E + BLK * VPT - 1) / (BLK * VPT); // 782

    k_init    <<<gInit, BLK,  0, stream>>>(gcurs, NC, stride, substride);
    k_bscatter<<<gScat, BLK,  0, stream>>>(src, dst, gcurs, bpack, E, NB, stride, substride);
    k_sortdeg <<<NB,    1024, 0, stream>>>(gcurs, bpack, x, dinv, xd8, ssrc, nstart,
                                           N, stride, substride, subrecip);
    k_agg1    <<<NB,    1024, 0, stream>>>(xd8, ssrc, nstart, dinv, W1, b1, W2, hs2, N);
    k_agg2    <<<NB,    1024, 0, stream>>>(hs2, ssrc, nstart, dinv, b2, out, N);
}

// Round 14
// 185.291 us; speedup vs baseline: 1.1529x; 1.0535x over previous
//
#include <hip/hip_runtime.h>
#include <cmath>

// GCN 2-layer: N=100k, E=3.2M, 5 -> 16 (relu) -> 3.
// R13: bscatter's remaining 48us / 35MB WRITE was the intrinsically
// uncoalesced write phase (16 scattered ints/thread). Now: block-local
// counting sort in LDS (reuse phase-1 ranks + 391-entry scan), stage
// {val, gaddr} bucket-sorted, then write slots linearly -> consecutive
// lanes hit consecutive addresses within each bucket run (full-line L2
// merges, XCD-mapping-independent). Claims/sub-frontiers unchanged.
// Pipeline: bucket edges by dst>>8 -> per-bucket counting sort by node ->
// register-accumulated gather aggregation (zero LDS atomics in agg).
// Factorization: agg[d] = dinv[d]*(xd[d] + sum_e xd[src_e]) @ W1, xd=x*dinv.

constexpr int BLK   = 256;
constexpr int VPT   = 16;    // edges/thread in bscatter (4096/block, 782 blocks)
constexpr int GPAD  = 16;    // cursors: one per 64B line
constexpr int NSUB  = 8;     // per-XCD sub-frontiers per bucket
constexpr int MAXIT = 10;    // sortdeg: stride <= 10240

// cursors: gcurs[(b*8+r)*GPAD] = b*stride + r*substride
__global__ void k_init(int* __restrict__ gcurs, int NC, int stride, int substride) {
    int i = blockIdx.x * BLK + threadIdx.x;
    if (i < NC) gcurs[i * GPAD] = (i >> 3) * stride + (i & 7) * substride;
}

// Partition edges into dst>>8 buckets; block-local counting sort in LDS,
// then coalesced run-writes into this block's XCD sub-region per bucket.
__global__ __launch_bounds__(BLK) void k_bscatter(
        const int* __restrict__ src, const int* __restrict__ dst,
        int* __restrict__ gcurs, int* __restrict__ bpack,
        int E, int NB, int stride, int substride) {
    __shared__ int lcnt[512];
    __shared__ int lsc[512];
    __shared__ int lbase[512];
    __shared__ int sval[BLK * VPT];
    __shared__ int sadr[BLK * VPT];
    int tid = threadIdx.x;
    int sub = blockIdx.x & (NSUB - 1);
    lcnt[tid] = 0; lcnt[tid + 256] = 0;
    __syncthreads();
    int e0 = blockIdx.x * (BLK * VPT);
    int pk[VPT];                     // (rank<<9)|bucket ; rank < 4096
#pragma unroll
    for (int j = 0; j < VPT; ++j) {
        int e = e0 + j * BLK + tid;
        if (e < E) {
            int b = dst[e] >> 8;
            int r = atomicAdd(&lcnt[b], 1);
            pk[j] = (r << 9) | b;
        } else pk[j] = -1;
    }
    __syncthreads();
    lsc[tid] = lcnt[tid]; lsc[tid + 256] = lcnt[tid + 256];
    __syncthreads();
    for (int off = 1; off < 512; off <<= 1) {    // inclusive scan, 512-wide
        int v0 = (tid >= off) ? lsc[tid - off] : 0;
        int t1 = tid + 256;
        int v1 = (t1 >= off) ? lsc[t1 - off] : 0;
        __syncthreads();
        lsc[tid] += v0; lsc[t1] += v1;
        __syncthreads();
    }
    for (int i = tid; i < NB; i += BLK) {        // bulk claims (XCD-local)
        int c = lcnt[i];
        lbase[i] = c ? atomicAdd(&gcurs[(i * NSUB + sub) * GPAD], c) : 0;
    }
    __syncthreads();
#pragma unroll
    for (int j = 0; j < VPT; ++j) {              // stage bucket-sorted
        if (pk[j] >= 0) {
            int e = e0 + j * BLK + tid;          // reload src/dst (L2-hot)
            int b = pk[j] & 511, r = pk[j] >> 9;
            int slot = lsc[b] - lcnt[b] + r;     // excl scan + rank
            int p = lbase[b] + r;
            sval[slot] = (src[e] << 8) | (dst[e] & 255);
            sadr[slot] = (p < b * stride + (sub + 1) * substride) ? p : -1;
        }
    }
    __syncthreads();
    int total = lsc[NB - 1];
    for (int s = tid; s < total; s += BLK) {     // coalesced run-writes
        int p = sadr[s];
        if (p >= 0) bpack[p] = sval[s];
    }
}

// Per bucket: count degrees over the 8 sub-ranges (atomicAdd returns
// within-node rank), block scan -> counting sort into per-node CSR runs
// (ssrc + nstart[257/bucket]). Also writes dinv and xd8 = {x*dinv, pad 32B}.
__global__ __launch_bounds__(1024) void k_sortdeg(
        const int* __restrict__ gcurs, const int* __restrict__ bpack,
        const float* __restrict__ x, float* __restrict__ dinv,
        float* __restrict__ xd8, int* __restrict__ ssrc,
        int* __restrict__ nstart, int N, int stride, int substride, int subrecip) {
    __shared__ int cnt[256];
    __shared__ int scan[256];
    __shared__ int subend[NSUB];
    int tid = threadIdx.x, b = blockIdx.x;
    if (tid < 256) cnt[tid] = 0;
    if (tid >= 256 && tid < 256 + NSUB) {
        int r = tid - 256;
        int sb = b * stride + r * substride;
        subend[r] = min(gcurs[(b * NSUB + r) * GPAD], sb + substride);
    }
    __syncthreads();
    int beg = b * stride;
    int rk[MAXIT], pkv[MAXIT];
    bool va[MAXIT];
#pragma unroll
    for (int j = 0; j < MAXIT; ++j) {
        int off = j * 1024 + tid;                // 0 .. stride-1
        int r = (off * subrecip) >> 24;          // off / substride (magic)
        int e = beg + off;
        bool v = (off < NSUB * substride) && (e < subend[r]);
        va[j] = v;
        int pk = v ? bpack[e] : 0;
        pkv[j] = pk;
        rk[j] = v ? atomicAdd(&cnt[pk & 255], 1) : 0;
    }
    __syncthreads();
    if (tid < 256) scan[tid] = cnt[tid];
    __syncthreads();
    for (int off = 1; off < 256; off <<= 1) {    // inclusive Hillis-Steele
        int v = 0;
        if (tid < 256 && tid >= off) v = scan[tid - off];
        __syncthreads();
        if (tid < 256) scan[tid] += v;
        __syncthreads();
    }
#pragma unroll
    for (int j = 0; j < MAXIT; ++j) {
        if (va[j]) {
            int d = pkv[j] & 255;
            int p = beg + scan[d] - cnt[d] + rk[j];   // excl prefix + rank
            ssrc[p] = pkv[j] >> 8;
        }
    }
    if (tid >= 256) return;
    nstart[b * 257 + tid] = beg + scan[tid] - cnt[tid];
    if (tid == 255) nstart[b * 257 + 256] = beg + scan[255];
    int node = b * 256 + tid;
    if (node >= N) return;
    float di = rsqrtf((float)(cnt[tid] + 1));    // +1 self-loop
    dinv[node] = di;
    float4 lo, hi;
    lo.x = x[(size_t)node * 5 + 0] * di;
    lo.y = x[(size_t)node * 5 + 1] * di;
    lo.z = x[(size_t)node * 5 + 2] * di;
    lo.w = x[(size_t)node * 5 + 3] * di;
    hi.x = x[(size_t)node * 5 + 4] * di;
    hi.y = 0.f; hi.z = 0.f; hi.w = 0.f;
    float4* o = reinterpret_cast<float4*>(xd8) + (size_t)node * 2;
    o[0] = lo; o[1] = hi;
}

// Layer-1 aggregate: 4 lanes per node walk its CSR run, register-accumulate
// 5 floats, shfl quad-reduce. Epilogue: +self, *dinv, @W1+b1, relu, @W2,
// *dinv -> hs2. No LDS atomics.
__global__ __launch_bounds__(1024) void k_agg1(
        const float* __restrict__ xd8, const int* __restrict__ ssrc,
        const int* __restrict__ nstart, const float* __restrict__ dinv,
        const float* __restrict__ W1, const float* __restrict__ b1,
        const float* __restrict__ W2, float* __restrict__ hs2, int N) {
    __shared__ float w1[80];
    __shared__ float w2[48];
    int tid = threadIdx.x, b = blockIdx.x;
    if (tid < 80) w1[tid] = W1[tid];
    else if (tid >= 128 && tid < 176) w2[tid - 128] = W2[tid - 128];
    __syncthreads();
    int n = tid >> 2, q = tid & 3;
    int node = b * 256 + n;
    int s0 = nstart[b * 257 + n];
    int s1 = nstart[b * 257 + n + 1];
    const float4* h4 = reinterpret_cast<const float4*>(xd8);
    float g0 = 0.f, g1 = 0.f, g2 = 0.f, g3 = 0.f, g4 = 0.f;
    int e = s0 + q;
    int sN = (e < s1) ? ssrc[e] : 0;             // 1-deep index prefetch
    while (e < s1) {
        int s = sN;
        int e2 = e + 4;
        sN = (e2 < s1) ? ssrc[e2] : 0;
        float4 lo = h4[(size_t)s * 2];
        float v4 = xd8[(size_t)s * 8 + 4];
        g0 += lo.x; g1 += lo.y; g2 += lo.z; g3 += lo.w; g4 += v4;
        e = e2;
    }
    g0 += __shfl_xor(g0, 1); g0 += __shfl_xor(g0, 2);
    g1 += __shfl_xor(g1, 1); g1 += __shfl_xor(g1, 2);
    g2 += __shfl_xor(g2, 1); g2 += __shfl_xor(g2, 2);
    g3 += __shfl_xor(g3, 1); g3 += __shfl_xor(g3, 2);
    g4 += __shfl_xor(g4, 1); g4 += __shfl_xor(g4, 2);
    if (q != 0 || node >= N) return;
    float di = dinv[node];
    const float* xs = &xd8[(size_t)node * 8];
    g0 += xs[0]; g1 += xs[1]; g2 += xs[2]; g3 += xs[3]; g4 += xs[4];
    float p0 = 0.f, p1 = 0.f, p2 = 0.f;
#pragma unroll
    for (int f = 0; f < 16; ++f) {
        float s = g0 * w1[f] + g1 * w1[16 + f] + g2 * w1[32 + f]
                + g3 * w1[48 + f] + g4 * w1[64 + f];
        float t = fmaxf(fmaf(di, s, b1[f]), 0.f);
        p0 = fmaf(t, w2[f * 3 + 0], p0);
        p1 = fmaf(t, w2[f * 3 + 1], p1);
        p2 = fmaf(t, w2[f * 3 + 2], p2);
    }
    float4 o = {p0 * di, p1 * di, p2 * di, 0.f};
    *reinterpret_cast<float4*>(&hs2[(size_t)node * 4]) = o;
}

// Layer-2 aggregate: same structure over hs2 (16B rows). No LDS atomics.
__global__ __launch_bounds__(1024) void k_agg2(
        const float* __restrict__ hs2, const int* __restrict__ ssrc,
        const int* __restrict__ nstart, const float* __restrict__ dinv,
        const float* __restrict__ b2, float* __restrict__ out, int N) {
    int tid = threadIdx.x, b = blockIdx.x;
    int n = tid >> 2, q = tid & 3;
    int node = b * 256 + n;
    int s0 = nstart[b * 257 + n];
    int s1 = nstart[b * 257 + n + 1];
    const float4* h4 = reinterpret_cast<const float4*>(hs2);
    float a0 = 0.f, a1 = 0.f, a2 = 0.f;
    int e = s0 + q;
    int sN = (e < s1) ? ssrc[e] : 0;
    while (e < s1) {
        int s = sN;
        int e2 = e + 4;
        sN = (e2 < s1) ? ssrc[e2] : 0;
        float4 v = h4[s];
        a0 += v.x; a1 += v.y; a2 += v.z;
        e = e2;
    }
    a0 += __shfl_xor(a0, 1); a0 += __shfl_xor(a0, 2);
    a1 += __shfl_xor(a1, 1); a1 += __shfl_xor(a1, 2);
    a2 += __shfl_xor(a2, 1); a2 += __shfl_xor(a2, 2);
    if (q != 0 || node >= N) return;
    float di = dinv[node];
    const float* hself = &hs2[(size_t)node * 4];
    out[(size_t)node * 3 + 0] = fmaf(di, a0 + hself[0], b2[0]);
    out[(size_t)node * 3 + 1] = fmaf(di, a1 + hself[1], b2[1]);
    out[(size_t)node * 3 + 2] = fmaf(di, a2 + hself[2], b2[2]);
}

// ---- launch ----------------------------------------------------------------

extern "C" void kernel_launch(void* const* d_in, const int* in_sizes, int n_in,
                              void* d_out, int out_size, void* d_ws, size_t ws_size,
                              hipStream_t stream) {
    const float* x  = (const float*)d_in[0];
    const int*   ei = (const int*)  d_in[1];
    const float* W1 = (const float*)d_in[2];
    const float* b1 = (const float*)d_in[3];
    const float* W2 = (const float*)d_in[4];
    const float* b2 = (const float*)d_in[5];
    float* out = (float*)d_out;

    const int N = in_sizes[0] / 5;
    const int E = in_sizes[1] / 2;
    const int* src = ei;
    const int* dst = ei + E;

    const int NB = (N + 255) >> 8;                       // 391 buckets
    int meanSub = (E + NB * NSUB - 1) / (NB * NSUB);     // ~1023 edges/(bkt,xcd)
    int substride = meanSub + (int)(8.0 * sqrt((double)meanSub)) + 1;
    substride = (substride + 63) & ~63;                  // 1280
    if (substride * NSUB > 1024 * MAXIT) substride = (1024 * MAXIT) / NSUB;
    int stride = substride * NSUB;                       // 10240
    int subrecip = ((1 << 24) + substride - 1) / substride;  // magic for /substride

    // Workspace (16B aligned), ~38MB total.
    char* ws = (char*)d_ws;
    size_t off = 0;
    auto alloc = [&](size_t bytes) -> void* {
        void* p = ws + off;
        off += (bytes + 15) & ~size_t(15);
        return p;
    };
    int*   gcurs  = (int*)  alloc((size_t)NB * NSUB * GPAD * 4);
    int*   bpack  = (int*)  alloc((size_t)NB * stride * 4);
    int*   ssrc   = (int*)  alloc((size_t)NB * stride * 4);
    int*   nstart = (int*)  alloc((size_t)NB * 257 * 4);
    float* dinv   = (float*)alloc((size_t)N * 4);
    float* xd8    = (float*)alloc((size_t)N * 8 * 4);
    float* hs2    = (float*)alloc((size_t)N * 4 * 4);
    (void)ws_size; (void)n_in; (void)out_size;

    const int NC    = NB * NSUB;                         // 3128 cursors
    const int gInit = (NC + BLK - 1) / BLK;
    const int gScat = (E + BLK * VPT - 1) / (BLK * VPT); // 782

    k_init    <<<gInit, BLK,  0, stream>>>(gcurs, NC, stride, substride);
    k_bscatter<<<gScat, BLK,  0, stream>>>(src, dst, gcurs, bpack, E, NB, stride, substride);
    k_sortdeg <<<NB,    1024, 0, stream>>>(gcurs, bpack, x, dinv, xd8, ssrc, nstart,
                                           N, stride, substride, subrecip);
    k_agg1    <<<NB,    1024, 0, stream>>>(xd8, ssrc, nstart, dinv, W1, b1, W2, hs2, N);
    k_agg2    <<<NB,    1024, 0, stream>>>(hs2, ssrc, nstart, dinv, b2, out, N);
}

// Round 18
// 184.015 us; speedup vs baseline: 1.1609x; 1.0069x over previous
//
#include <hip/hip_runtime.h>
#include <cmath>

// GCN 2-layer: N=100k, E=3.2M, 5 -> 16 (relu) -> 3.
// R18: REVERT to the R13/R14-green bscatter geometry (BLK=256, VPT=16,
// 782 blocks, staged bucket-sorted writes). R15's SBLK=1024 variant failed
// the post-timing determinism check (~1-edge divergence, unexplained);
// R12/R13 geometry has 3 green benches. One safe change vs R13: val[] is
// captured in registers in phase 1 (bit-identical slot values, no reload
// of src/dst = -25.6MB L2 reads; no atomic/claim logic touched).
// Pipeline: bucket edges by dst>>8 -> per-bucket counting sort by node ->
// register-accumulated gather aggregation (zero LDS atomics in agg).
// Factorization: agg[d] = dinv[d]*(xd[d] + sum_e xd[src_e]) @ W1, xd=x*dinv.

constexpr int BLK   = 256;
constexpr int VPT   = 16;    // edges/thread in bscatter (4096/block, 782 blocks)
constexpr int GPAD  = 16;    // cursors: one per 64B line
constexpr int NSUB  = 8;     // per-XCD sub-frontiers per bucket
constexpr int MAXIT = 10;    // sortdeg: stride <= 10240

// cursors: gcurs[(b*8+r)*GPAD] = b*stride + r*substride
__global__ void k_init(int* __restrict__ gcurs, int NC, int stride, int substride) {
    int i = blockIdx.x * BLK + threadIdx.x;
    if (i < NC) gcurs[i * GPAD] = (i >> 3) * stride + (i & 7) * substride;
}

// Partition edges into dst>>8 buckets; block-local counting sort in LDS,
// then coalesced run-writes into this block's XCD sub-region per bucket.
__global__ __launch_bounds__(BLK) void k_bscatter(
        const int* __restrict__ src, const int* __restrict__ dst,
        int* __restrict__ gcurs, int* __restrict__ bpack,
        int E, int NB, int stride, int substride) {
    __shared__ int lcnt[512];
    __shared__ int lsc[512];
    __shared__ int lbase[512];
    __shared__ int sval[BLK * VPT];
    __shared__ int sadr[BLK * VPT];
    int tid = threadIdx.x;
    int sub = blockIdx.x & (NSUB - 1);
    lcnt[tid] = 0; lcnt[tid + 256] = 0;
    __syncthreads();
    int e0 = blockIdx.x * (BLK * VPT);
    int pk[VPT];                     // (rank<<9)|bucket ; rank < 4096
    int val[VPT];                    // (src<<8)|(dst&255), captured phase 1
#pragma unroll
    for (int j = 0; j < VPT; ++j) {
        int e = e0 + j * BLK + tid;
        if (e < E) {
            int s = src[e], d = dst[e];
            int b = d >> 8;
            int r = atomicAdd(&lcnt[b], 1);
            pk[j]  = (r << 9) | b;
            val[j] = (s << 8) | (d & 255);
        } else pk[j] = -1;
    }
    __syncthreads();
    lsc[tid] = lcnt[tid]; lsc[tid + 256] = lcnt[tid + 256];
    __syncthreads();
    for (int off = 1; off < 512; off <<= 1) {    // inclusive scan, 512-wide
        int v0 = (tid >= off) ? lsc[tid - off] : 0;
        int t1 = tid + 256;
        int v1 = (t1 >= off) ? lsc[t1 - off] : 0;
        __syncthreads();
        lsc[tid] += v0; lsc[t1] += v1;
        __syncthreads();
    }
    for (int i = tid; i < NB; i += BLK) {        // bulk claims (XCD-sub-local)
        int c = lcnt[i];
        lbase[i] = c ? atomicAdd(&gcurs[(i * NSUB + sub) * GPAD], c) : 0;
    }
    __syncthreads();
#pragma unroll
    for (int j = 0; j < VPT; ++j) {              // stage bucket-sorted
        if (pk[j] >= 0) {
            int b = pk[j] & 511, r = pk[j] >> 9;
            int slot = lsc[b] - lcnt[b] + r;     // excl scan + rank
            int p = lbase[b] + r;
            sval[slot] = val[j];
            sadr[slot] = (p < b * stride + (sub + 1) * substride) ? p : -1;
        }
    }
    __syncthreads();
    int total = lsc[NB - 1];
    for (int s = tid; s < total; s += BLK) {     // coalesced run-writes
        int p = sadr[s];
        if (p >= 0) bpack[p] = sval[s];
    }
}

// Per bucket: count degrees over the 8 sub-ranges (atomicAdd returns
// within-node rank), block scan -> counting sort into per-node CSR runs
// (ssrc + nstart[257/bucket]). Also writes dinv and xd8 = {x*dinv, pad 32B}.
__global__ __launch_bounds__(1024) void k_sortdeg(
        const int* __restrict__ gcurs, const int* __restrict__ bpack,
        const float* __restrict__ x, float* __restrict__ dinv,
        float* __restrict__ xd8, int* __restrict__ ssrc,
        int* __restrict__ nstart, int N, int stride, int substride, int subrecip) {
    __shared__ int cnt[256];
    __shared__ int scan[256];
    __shared__ int subend[NSUB];
    int tid = threadIdx.x, b = blockIdx.x;
    if (tid < 256) cnt[tid] = 0;
    if (tid >= 256 && tid < 256 + NSUB) {
        int r = tid - 256;
        int sb = b * stride + r * substride;
        subend[r] = min(gcurs[(b * NSUB + r) * GPAD], sb + substride);
    }
    __syncthreads();
    int beg = b * stride;
    int rk[MAXIT], pkv[MAXIT];
    bool va[MAXIT];
#pragma unroll
    for (int j = 0; j < MAXIT; ++j) {
        int off = j * 1024 + tid;                // 0 .. stride-1
        int r = (off * subrecip) >> 24;          // off / substride (magic)
        int e = beg + off;
        bool v = (off < NSUB * substride) && (e < subend[r]);
        va[j] = v;
        int pk = v ? bpack[e] : 0;
        pkv[j] = pk;
        rk[j] = v ? atomicAdd(&cnt[pk & 255], 1) : 0;
    }
    __syncthreads();
    if (tid < 256) scan[tid] = cnt[tid];
    __syncthreads();
    for (int off = 1; off < 256; off <<= 1) {    // inclusive Hillis-Steele
        int v = 0;
        if (tid < 256 && tid >= off) v = scan[tid - off];
        __syncthreads();
        if (tid < 256) scan[tid] += v;
        __syncthreads();
    }
#pragma unroll
    for (int j = 0; j < MAXIT; ++j) {
        if (va[j]) {
            int d = pkv[j] & 255;
            int p = beg + scan[d] - cnt[d] + rk[j];   // excl prefix + rank
            ssrc[p] = pkv[j] >> 8;
        }
    }
    if (tid >= 256) return;
    nstart[b * 257 + tid] = beg + scan[tid] - cnt[tid];
    if (tid == 255) nstart[b * 257 + 256] = beg + scan[255];
    int node = b * 256 + tid;
    if (node >= N) return;
    float di = rsqrtf((float)(cnt[tid] + 1));    // +1 self-loop
    dinv[node] = di;
    float4 lo, hi;
    lo.x = x[(size_t)node * 5 + 0] * di;
    lo.y = x[(size_t)node * 5 + 1] * di;
    lo.z = x[(size_t)node * 5 + 2] * di;
    lo.w = x[(size_t)node * 5 + 3] * di;
    hi.x = x[(size_t)node * 5 + 4] * di;
    hi.y = 0.f; hi.z = 0.f; hi.w = 0.f;
    float4* o = reinterpret_cast<float4*>(xd8) + (size_t)node * 2;
    o[0] = lo; o[1] = hi;
}

// Layer-1 aggregate: 4 lanes per node walk its CSR run, register-accumulate
// 5 floats, shfl quad-reduce. Epilogue: +self, *dinv, @W1+b1, relu, @W2,
// *dinv -> hs2. No LDS atomics.
__global__ __launch_bounds__(1024) void k_agg1(
        const float* __restrict__ xd8, const int* __restrict__ ssrc,
        const int* __restrict__ nstart, const float* __restrict__ dinv,
        const float* __restrict__ W1, const float* __restrict__ b1,
        const float* __restrict__ W2, float* __restrict__ hs2, int N) {
    __shared__ float w1[80];
    __shared__ float w2[48];
    int tid = threadIdx.x, b = blockIdx.x;
    if (tid < 80) w1[tid] = W1[tid];
    else if (tid >= 128 && tid < 176) w2[tid - 128] = W2[tid - 128];
    __syncthreads();
    int n = tid >> 2, q = tid & 3;
    int node = b * 256 + n;
    int s0 = nstart[b * 257 + n];
    int s1 = nstart[b * 257 + n + 1];
    const float4* h4 = reinterpret_cast<const float4*>(xd8);
    float g0 = 0.f, g1 = 0.f, g2 = 0.f, g3 = 0.f, g4 = 0.f;
    int e = s0 + q;
    int sN = (e < s1) ? ssrc[e] : 0;             // 1-deep index prefetch
    while (e < s1) {
        int s = sN;
        int e2 = e + 4;
        sN = (e2 < s1) ? ssrc[e2] : 0;
        float4 lo = h4[(size_t)s * 2];
        float v4 = xd8[(size_t)s * 8 + 4];
        g0 += lo.x; g1 += lo.y; g2 += lo.z; g3 += lo.w; g4 += v4;
        e = e2;
    }
    g0 += __shfl_xor(g0, 1); g0 += __shfl_xor(g0, 2);
    g1 += __shfl_xor(g1, 1); g1 += __shfl_xor(g1, 2);
    g2 += __shfl_xor(g2, 1); g2 += __shfl_xor(g2, 2);
    g3 += __shfl_xor(g3, 1); g3 += __shfl_xor(g3, 2);
    g4 += __shfl_xor(g4, 1); g4 += __shfl_xor(g4, 2);
    if (q != 0 || node >= N) return;
    float di = dinv[node];
    const float* xs = &xd8[(size_t)node * 8];
    g0 += xs[0]; g1 += xs[1]; g2 += xs[2]; g3 += xs[3]; g4 += xs[4];
    float p0 = 0.f, p1 = 0.f, p2 = 0.f;
#pragma unroll
    for (int f = 0; f < 16; ++f) {
        float s = g0 * w1[f] + g1 * w1[16 + f] + g2 * w1[32 + f]
                + g3 * w1[48 + f] + g4 * w1[64 + f];
        float t = fmaxf(fmaf(di, s, b1[f]), 0.f);
        p0 = fmaf(t, w2[f * 3 + 0], p0);
        p1 = fmaf(t, w2[f * 3 + 1], p1);
        p2 = fmaf(t, w2[f * 3 + 2], p2);
    }
    float4 o = {p0 * di, p1 * di, p2 * di, 0.f};
    *reinterpret_cast<float4*>(&hs2[(size_t)node * 4]) = o;
}

// Layer-2 aggregate: same structure over hs2 (16B rows). No LDS atomics.
__global__ __launch_bounds__(1024) void k_agg2(
        const float* __restrict__ hs2, const int* __restrict__ ssrc,
        const int* __restrict__ nstart, const float* __restrict__ dinv,
        const float* __restrict__ b2, float* __restrict__ out, int N) {
    int tid = threadIdx.x, b = blockIdx.x;
    int n = tid >> 2, q = tid & 3;
    int node = b * 256 + n;
    int s0 = nstart[b * 257 + n];
    int s1 = nstart[b * 257 + n + 1];
    const float4* h4 = reinterpret_cast<const float4*>(hs2);
    float a0 = 0.f, a1 = 0.f, a2 = 0.f;
    int e = s0 + q;
    int sN = (e < s1) ? ssrc[e] : 0;
    while (e < s1) {
        int s = sN;
        int e2 = e + 4;
        sN = (e2 < s1) ? ssrc[e2] : 0;
        float4 v = h4[s];
        a0 += v.x; a1 += v.y; a2 += v.z;
        e = e2;
    }
    a0 += __shfl_xor(a0, 1); a0 += __shfl_xor(a0, 2);
    a1 += __shfl_xor(a1, 1); a1 += __shfl_xor(a1, 2);
    a2 += __shfl_xor(a2, 1); a2 += __shfl_xor(a2, 2);
    if (q != 0 || node >= N) return;
    float di = dinv[node];
    const float* hself = &hs2[(size_t)node * 4];
    out[(size_t)node * 3 + 0] = fmaf(di, a0 + hself[0], b2[0]);
    out[(size_t)node * 3 + 1] = fmaf(di, a1 + hself[1], b2[1]);
    out[(size_t)node * 3 + 2] = fmaf(di, a2 + hself[2], b2[2]);
}

// ---- launch ----------------------------------------------------------------

extern "C" void kernel_launch(void* const* d_in, const int* in_sizes, int n_in,
                              void* d_out, int out_size, void* d_ws, size_t ws_size,
                              hipStream_t stream) {
    const float* x  = (const float*)d_in[0];
    const int*   ei = (const int*)  d_in[1];
    const float* W1 = (const float*)d_in[2];
    const float* b1 = (const float*)d_in[3];
    const float* W2 = (const float*)d_in[4];
    const float* b2 = (const float*)d_in[5];
    float* out = (float*)d_out;

    const int N = in_sizes[0] / 5;
    const int E = in_sizes[1] / 2;
    const int* src = ei;
    const int* dst = ei + E;

    const int NB = (N + 255) >> 8;                       // 391 buckets
    int meanSub = (E + NB * NSUB - 1) / (NB * NSUB);     // ~1024 edges/(bkt,xcd)
    int substride = meanSub + (int)(8.0 * sqrt((double)meanSub)) + 1;
    substride = (substride + 63) & ~63;
    if (substride * NSUB > 1024 * MAXIT) substride = (1024 * MAXIT) / NSUB;
    int stride = substride * NSUB;                       // 10240
    int subrecip = ((1 << 24) + substride - 1) / substride;  // magic for /substride

    // Workspace (16B aligned), ~38MB total.
    char* ws = (char*)d_ws;
    size_t off = 0;
    auto alloc = [&](size_t bytes) -> void* {
        void* p = ws + off;
        off += (bytes + 15) & ~size_t(15);
        return p;
    };
    int*   gcurs  = (int*)  alloc((size_t)NB * NSUB * GPAD * 4);
    int*   bpack  = (int*)  alloc((size_t)NB * stride * 4);
    int*   ssrc   = (int*)  alloc((size_t)NB * stride * 4);
    int*   nstart = (int*)  alloc((size_t)NB * 257 * 4);
    float* dinv   = (float*)alloc((size_t)N * 4);
    float* xd8    = (float*)alloc((size_t)N * 8 * 4);
    float* hs2    = (float*)alloc((size_t)N * 4 * 4);
    (void)ws_size; (void)n_in; (void)out_size;

    const int NC    = NB * NSUB;                         // 3128 cursors
    const int gInit = (NC + BLK - 1) / BLK;
    const int gScat = (E + BLK * VPT - 1) / (BLK * VPT); // 782

    k_init    <<<gInit, BLK,  0, stream>>>(gcurs, NC, stride, substride);
    k_bscatter<<<gScat, BLK,  0, stream>>>(src, dst, gcurs, bpack, E, NB, stride, substride);
    k_sortdeg <<<NB,    1024, 0, stream>>>(gcurs, bpack, x, dinv, xd8, ssrc, nstart,
                                           N, stride, substride, subrecip);
    k_agg1    <<<NB,    1024, 0, stream>>>(xd8, ssrc, nstart, dinv, W1, b1, W2, hs2, N);
    k_agg2    <<<NB,    1024, 0, stream>>>(hs2, ssrc, nstart, dinv, b2, out, N);
}